// Round 1
// baseline (73.050 us; speedup 1.0000x reference)
//
#include <hip/hip_runtime.h>

#define NB 4      // B
#define NS 512    // S
#define NSC 128   // SC
#define NMC 64    // MC
#define NR 32     // R
#define NO 64     // O
#define NHID 256  // 4*O

__device__ __forceinline__ float wave_sum(float v) {
    #pragma unroll
    for (int m = 1; m < 64; m <<= 1) v += __shfl_xor(v, m, 64);
    return v;
}
__device__ __forceinline__ float wave_max(float v) {
    #pragma unroll
    for (int m = 1; m < 64; m <<= 1) v = fmaxf(v, __shfl_xor(v, m, 64));
    return v;
}

// --- K1: q,k projections: one block (64 thr) per (b,s) row --------------
__global__ __launch_bounds__(64) void qk_kernel(
    const float* __restrict__ seq,
    const float* __restrict__ Wq, const float* __restrict__ bq,
    const float* __restrict__ Wk, const float* __restrict__ bk,
    float* __restrict__ q, float* __restrict__ k) {
    int bs  = blockIdx.x;         // 0..B*S-1
    int tid = threadIdx.x;        // 0..63
    __shared__ float srow[NSC];
    const float* sp = seq + (size_t)bs * NSC;
    srow[tid]      = sp[tid];
    srow[tid + 64] = sp[tid + 64];
    __syncthreads();
    int r = tid & 31;
    const float* W    = (tid < 32) ? Wq : Wk;
    const float* bias = (tid < 32) ? bq : bk;
    float acc = bias[r];
    #pragma unroll 8
    for (int c = 0; c < NSC; ++c) acc += srow[c] * W[c * NR + r];
    float* dst = (tid < 32) ? q : k;
    dst[(size_t)bs * NR + r] = acc;
}

// --- K2: fused softmax + attn-pool over map_ + Wv + LN + MLP ------------
// one block (256 thr = 4 waves) per (b,s) row
__global__ __launch_bounds__(256) void main_kernel(
    const float* __restrict__ map_,
    const float* __restrict__ q, const float* __restrict__ k,
    const float* __restrict__ Wv, const float* __restrict__ bv,
    const float* __restrict__ gamma, const float* __restrict__ beta,
    const float* __restrict__ W1, const float* __restrict__ b1,
    const float* __restrict__ W2, const float* __restrict__ b2,
    float* __restrict__ out) {
    const float DENOM_INV = 0.17677669529663687f;  // 1/sqrt(32)
    const float LN_EPS = 1e-5f;

    int bs   = blockIdx.x;
    int b    = bs >> 9;       // / 512
    int s    = bs & 511;
    int tid  = threadIdx.x;
    int lane = tid & 63;
    int wave = tid >> 6;

    __shared__ float s_q[NR];
    __shared__ float s_attn[NS];
    __shared__ float s_red[8];
    __shared__ float s_m[NMC];
    __shared__ float s_score[NMC];
    __shared__ float s_h[NHID];

    if (tid < NR) s_q[tid] = q[(size_t)bs * NR + tid];
    __syncthreads();

    // ---- logits for t = tid and t = tid+256 ----
    const float* kb = k + (size_t)b * NS * NR;
    float lg0, lg1;
    {
        const float* kr0 = kb + (size_t)tid * NR;
        const float* kr1 = kb + (size_t)(tid + 256) * NR;
        float a0 = 0.f, a1 = 0.f;
        #pragma unroll
        for (int r = 0; r < NR; ++r) {
            a0 += s_q[r] * kr0[r];
            a1 += s_q[r] * kr1[r];
        }
        lg0 = a0 * DENOM_INV;
        lg1 = a1 * DENOM_INV;
    }

    // ---- block softmax over 512 ----
    float mx = wave_max(fmaxf(lg0, lg1));
    if (lane == 0) s_red[wave] = mx;
    __syncthreads();
    mx = fmaxf(fmaxf(s_red[0], s_red[1]), fmaxf(s_red[2], s_red[3]));
    float e0 = expf(lg0 - mx), e1 = expf(lg1 - mx);
    float ssum = wave_sum(e0 + e1);
    if (lane == 0) s_red[4 + wave] = ssum;
    __syncthreads();
    float inv = 1.f / (s_red[4] + s_red[5] + s_red[6] + s_red[7]);
    s_attn[tid]       = e0 * inv;
    s_attn[tid + 256] = e1 * inv;
    __syncthreads();

    // ---- m[d] = sum_t attn[t] * map_[b,d,s,t]  (the 256 MB stream) ----
    const float4* attn4 = (const float4*)s_attn;
    float4 w0 = attn4[lane];
    float4 w1 = attn4[lane + 64];
    for (int d = wave; d < NMC; d += 4) {
        const float4* mp4 = (const float4*)(map_ + (((size_t)b * NMC + d) * NS + s) * NS);
        float4 a0 = mp4[lane];
        float4 a1 = mp4[lane + 64];
        float acc = a0.x * w0.x + a0.y * w0.y + a0.z * w0.z + a0.w * w0.w
                  + a1.x * w1.x + a1.y * w1.y + a1.z * w1.z + a1.w * w1.w;
        acc = wave_sum(acc);
        if (lane == 0) s_m[d] = acc;
    }
    __syncthreads();

    // ---- pooled = m @ Wv + bv, then LN (wave 0 only, tid==channel) ----
    if (tid < NMC) {
        float pooled = bv[tid];
        #pragma unroll 8
        for (int d = 0; d < NMC; ++d) pooled += s_m[d] * Wv[d * NMC + tid];
        float sum   = wave_sum(pooled);
        float sumsq = wave_sum(pooled * pooled);
        float mu  = sum * (1.f / NMC);
        float var = sumsq * (1.f / NMC) - mu * mu;
        float rsig = rsqrtf(var + LN_EPS);
        s_score[tid] = (pooled - mu) * rsig * gamma[tid] + beta[tid];
    }
    __syncthreads();

    // ---- h = relu(score @ W1 + b1): thread tid owns hidden unit tid ----
    {
        float hacc = b1[tid];
        #pragma unroll 8
        for (int c = 0; c < NMC; ++c) hacc += s_score[c] * W1[c * NHID + tid];
        s_h[tid] = fmaxf(hacc, 0.f);
    }
    __syncthreads();

    // ---- out = h @ W2 + b2 ----
    if (tid < NO) {
        float oacc = b2[tid];
        #pragma unroll 8
        for (int j = 0; j < NHID; ++j) oacc += s_h[j] * W2[j * NO + tid];
        out[(size_t)bs * NO + tid] = oacc;
    }
}

extern "C" void kernel_launch(void* const* d_in, const int* in_sizes, int n_in,
                              void* d_out, int out_size, void* d_ws, size_t ws_size,
                              hipStream_t stream) {
    const float* map_  = (const float*)d_in[0];
    const float* seq   = (const float*)d_in[1];
    const float* Wq    = (const float*)d_in[2];
    const float* bq    = (const float*)d_in[3];
    const float* Wk    = (const float*)d_in[4];
    const float* bk    = (const float*)d_in[5];
    const float* Wv    = (const float*)d_in[6];
    const float* bv    = (const float*)d_in[7];
    const float* gamma = (const float*)d_in[8];
    const float* beta  = (const float*)d_in[9];
    const float* W1    = (const float*)d_in[10];
    const float* b1    = (const float*)d_in[11];
    const float* W2    = (const float*)d_in[12];
    const float* b2    = (const float*)d_in[13];
    float* out = (float*)d_out;

    float* q = (float*)d_ws;                      // B*S*R floats
    float* kk = q + (size_t)NB * NS * NR;         // B*S*R floats

    qk_kernel<<<NB * NS, 64, 0, stream>>>(seq, Wq, bq, Wk, bk, q, kk);
    main_kernel<<<NB * NS, 256, 0, stream>>>(map_, q, kk, Wv, bv, gamma, beta,
                                             W1, b1, W2, b2, out);
}

// Round 2
// 69.759 us; speedup vs baseline: 1.0472x; 1.0472x over previous
//
#include <hip/hip_runtime.h>

#define NB 4      // B
#define NS 512    // S
#define NSC 128   // SC
#define NMC 64    // MC
#define NR 32     // R
#define NO 64     // O
#define NHID 256  // 4*O

__device__ __forceinline__ float wave_sum(float v) {
    #pragma unroll
    for (int m = 1; m < 64; m <<= 1) v += __shfl_xor(v, m, 64);
    return v;
}
__device__ __forceinline__ float wave_max(float v) {
    #pragma unroll
    for (int m = 1; m < 64; m <<= 1) v = fmaxf(v, __shfl_xor(v, m, 64));
    return v;
}

// --- K1: q,k projections: one block (64 thr) per (b,s) row --------------
__global__ __launch_bounds__(64) void qk_kernel(
    const float* __restrict__ seq,
    const float* __restrict__ Wq, const float* __restrict__ bq,
    const float* __restrict__ Wk, const float* __restrict__ bk,
    float* __restrict__ q, float* __restrict__ k) {
    int bs  = blockIdx.x;         // 0..B*S-1
    int tid = threadIdx.x;        // 0..63
    __shared__ float srow[NSC];
    const float* sp = seq + (size_t)bs * NSC;
    srow[tid]      = sp[tid];
    srow[tid + 64] = sp[tid + 64];
    __syncthreads();
    int r = tid & 31;
    const float* W    = (tid < 32) ? Wq : Wk;
    const float* bias = (tid < 32) ? bq : bk;
    float acc = bias[r];
    #pragma unroll 8
    for (int c = 0; c < NSC; ++c) acc += srow[c] * W[c * NR + r];
    float* dst = (tid < 32) ? q : k;
    dst[(size_t)bs * NR + r] = acc;
}

// --- K2: fused softmax + attn-pool over map_ + Wv + LN + MLP ------------
// one block (256 thr = 4 waves) per (b,s) row
__global__ __launch_bounds__(256) void main_kernel(
    const float* __restrict__ map_,
    const float* __restrict__ q, const float* __restrict__ k,
    const float* __restrict__ Wv, const float* __restrict__ bv,
    const float* __restrict__ gamma, const float* __restrict__ beta,
    const float* __restrict__ W1, const float* __restrict__ b1,
    const float* __restrict__ W2, const float* __restrict__ b2,
    float* __restrict__ out) {
    const float DENOM_INV = 0.17677669529663687f;  // 1/sqrt(32)
    const float LN_EPS = 1e-5f;

    int bs   = blockIdx.x;
    int b    = bs >> 9;       // / 512
    int s    = bs & 511;
    int tid  = threadIdx.x;
    int lane = tid & 63;
    int wave = tid >> 6;

    __shared__ float s_q[NR];
    __shared__ float s_attn[NS];
    __shared__ float s_red[8];
    __shared__ float s_m[NMC];
    __shared__ float s_part[NMC][65];   // per-lane partials, +1 pad (2-way = free)

    float* s_flat  = &s_part[0][0];     // s_part is dead after the m-reduce:
    float* s_score = s_flat;            // reuse for LN output (64 floats)
    float* s_h     = s_flat + 64;       // and MLP hidden (256 floats)

    if (tid < NR) s_q[tid] = q[(size_t)bs * NR + tid];
    __syncthreads();

    // ---- logits for t = tid and t = tid+256 (k is L2-resident) ----
    const float* kb = k + (size_t)b * NS * NR;
    float lg0, lg1;
    {
        const float4* q4 = (const float4*)s_q;                      // broadcast reads
        const float4* k0 = (const float4*)(kb + (size_t)tid * NR);
        const float4* k1 = (const float4*)(kb + (size_t)(tid + 256) * NR);
        float a0 = 0.f, a1 = 0.f;
        #pragma unroll
        for (int r4 = 0; r4 < NR / 4; ++r4) {
            float4 qv = q4[r4], kv0 = k0[r4], kv1 = k1[r4];
            a0 += qv.x * kv0.x + qv.y * kv0.y + qv.z * kv0.z + qv.w * kv0.w;
            a1 += qv.x * kv1.x + qv.y * kv1.y + qv.z * kv1.z + qv.w * kv1.w;
        }
        lg0 = a0 * DENOM_INV;
        lg1 = a1 * DENOM_INV;
    }

    // ---- block softmax over 512 (store UNNORMALIZED e; fold 1/sum later) ----
    float mx = wave_max(fmaxf(lg0, lg1));
    if (lane == 0) s_red[wave] = mx;
    __syncthreads();
    mx = fmaxf(fmaxf(s_red[0], s_red[1]), fmaxf(s_red[2], s_red[3]));
    float e0 = expf(lg0 - mx), e1 = expf(lg1 - mx);
    s_attn[tid]       = e0;
    s_attn[tid + 256] = e1;
    float ssum = wave_sum(e0 + e1);
    if (lane == 0) s_red[4 + wave] = ssum;
    __syncthreads();
    float inv = 1.f / (s_red[4] + s_red[5] + s_red[6] + s_red[7]);

    // ---- per-lane weights: t in [4*lane,4*lane+4) and [256+4*lane, ...) ----
    const float4* attn4 = (const float4*)s_attn;
    float4 w0 = attn4[lane];
    float4 w1 = attn4[lane + 64];
    w0.x *= inv; w0.y *= inv; w0.z *= inv; w0.w *= inv;
    w1.x *= inv; w1.y *= inv; w1.z *= inv; w1.w *= inv;

    // ---- m[d] = sum_t attn[t] * map_[b,d,s,t]  (the 268 MB stream) ----
    // wave w owns d in [16w, 16w+16); iterations are pure load+FMA+LDS-store
    {
        int d0 = wave * 16;
        const float4* base =
            (const float4*)(map_ + (((size_t)b * NMC + d0) * NS + s) * NS);
        #pragma unroll
        for (int i = 0; i < 16; ++i) {
            const float4* rp = base + (size_t)i * (NS * NS / 4);
            float4 a0 = rp[lane];
            float4 a1 = rp[lane + 64];
            float acc = a0.x * w0.x + a0.y * w0.y + a0.z * w0.z + a0.w * w0.w
                      + a1.x * w1.x + a1.y * w1.y + a1.z * w1.z + a1.w * w1.w;
            s_part[d0 + i][lane] = acc;
        }
    }
    __syncthreads();

    // ---- single cross-lane reduce: m[d] = sum over 64 lane-partials ----
    if (tid < NMC) {
        float acc = 0.f;
        #pragma unroll 8
        for (int i = 0; i < 64; ++i) acc += s_part[tid][i];
        s_m[tid] = acc;
    }
    __syncthreads();   // also: s_part dead from here; s_score/s_h may alias

    // ---- pooled = m @ Wv + bv, then LN (tid<64 == wave 0) ----
    if (tid < NMC) {
        float pooled = bv[tid];
        #pragma unroll 8
        for (int d = 0; d < NMC; ++d) pooled += s_m[d] * Wv[d * NMC + tid];
        float sum   = wave_sum(pooled);
        float sumsq = wave_sum(pooled * pooled);
        float mu  = sum * (1.f / NMC);
        float var = sumsq * (1.f / NMC) - mu * mu;
        float rsig = rsqrtf(var + LN_EPS);
        s_score[tid] = (pooled - mu) * rsig * gamma[tid] + beta[tid];
    }
    __syncthreads();

    // ---- h = relu(score @ W1 + b1): thread tid owns hidden unit tid ----
    {
        float hacc = b1[tid];
        #pragma unroll 8
        for (int c = 0; c < NMC; ++c) hacc += s_score[c] * W1[c * NHID + tid];
        s_h[tid] = fmaxf(hacc, 0.f);
    }
    __syncthreads();

    // ---- out = h @ W2 + b2 ----
    if (tid < NO) {
        float oacc = b2[tid];
        #pragma unroll 8
        for (int j = 0; j < NHID; ++j) oacc += s_h[j] * W2[j * NO + tid];
        out[(size_t)bs * NO + tid] = oacc;
    }
}

extern "C" void kernel_launch(void* const* d_in, const int* in_sizes, int n_in,
                              void* d_out, int out_size, void* d_ws, size_t ws_size,
                              hipStream_t stream) {
    const float* map_  = (const float*)d_in[0];
    const float* seq   = (const float*)d_in[1];
    const float* Wq    = (const float*)d_in[2];
    const float* bq    = (const float*)d_in[3];
    const float* Wk    = (const float*)d_in[4];
    const float* bk    = (const float*)d_in[5];
    const float* Wv    = (const float*)d_in[6];
    const float* bv    = (const float*)d_in[7];
    const float* gamma = (const float*)d_in[8];
    const float* beta  = (const float*)d_in[9];
    const float* W1    = (const float*)d_in[10];
    const float* b1    = (const float*)d_in[11];
    const float* W2    = (const float*)d_in[12];
    const float* b2    = (const float*)d_in[13];
    float* out = (float*)d_out;

    float* q = (float*)d_ws;                      // B*S*R floats
    float* kk = q + (size_t)NB * NS * NR;         // B*S*R floats

    qk_kernel<<<NB * NS, 64, 0, stream>>>(seq, Wq, bq, Wk, bk, q, kk);
    main_kernel<<<NB * NS, 256, 0, stream>>>(map_, q, kk, Wv, bv, gamma, beta,
                                             W1, b1, W2, b2, out);
}